// Round 1
// baseline (100488.123 us; speedup 1.0000x reference)
//
#include <hip/hip_runtime.h>
#include <cstdint>
#include <cstddef>

#define Bsz 32
#define Tn  2048
#define Dn  64
#define Hn  512
#define Cn  10
#define NG  32   // gate-unit groups (16 h-units each)
#define UG  16   // units per group
#define NBG 8    // batch groups
#define BPG 4    // batches per group
#define KS  32   // K-split lanes
#define RPC 4    // local gate-rows per cell (48 local rows = 3 gates x 16 units)
#define NTH 384  // 12 cells x 32 ks

__device__ __forceinline__ float sigmoidf_(float v) { return 1.f / (1.f + __expf(-v)); }

// hT layout: h[k][b] transposed with per-16-k skew: off(k,b) = k*4 + ((k>>4)<<2) + b
// max off = 511*4 + 124 + 3 = 2171 -> size 2176 floats (~8.7 KB)

__global__ __launch_bounds__(NTH) void gru_main(
    const float* __restrict__ x, const float* __restrict__ w_ih,
    const float* __restrict__ w_hh, const float* __restrict__ b_ih,
    const float* __restrict__ b_hh, float* __restrict__ hs,
    unsigned int* flags)
{
  const int g    = blockIdx.x & (NG - 1);
  const int bg   = blockIdx.x >> 5;
  const int tid  = threadIdx.x;
  const int ks   = tid & (KS - 1);
  const int cell = tid >> 5;   // 0..11

  __shared__ float hT[2176];
  __shared__ float xT[256];       // x_t transposed: [d][b]
  __shared__ float preS[48 * 4];  // r,z sums + n x-part   [local_row][b]
  __shared__ float preN[16 * 4];  // n h-part (gh_n + b_hh) [unit][b]

  // persistent per-thread weights (stay in VGPRs across all 2048 steps)
  float wreg[RPC][16];
  float wxreg[RPC][2];
  float bihr[RPC], bhhr[RPC];

  #pragma unroll
  for (int i = 0; i < RPC; ++i) {
    const int lr    = cell * RPC + i;   // 0..47 ; gate = lr>>4, unit = lr&15
    const int gamma = lr >> 4;
    const int u     = lr & 15;
    const int grow  = gamma * Hn + g * UG + u;
    const float4* wp = (const float4*)(w_hh + (size_t)grow * Hn + ks * 16);
    #pragma unroll
    for (int q = 0; q < 4; ++q) {
      const float4 v = wp[q];
      wreg[i][q * 4 + 0] = v.x; wreg[i][q * 4 + 1] = v.y;
      wreg[i][q * 4 + 2] = v.z; wreg[i][q * 4 + 3] = v.w;
    }
    wxreg[i][0] = w_ih[(size_t)grow * Dn + ks * 2 + 0];
    wxreg[i][1] = w_ih[(size_t)grow * Dn + ks * 2 + 1];
    bihr[i] = b_ih[grow];
    bhhr[i] = b_hh[grow];
  }

  for (int idx = tid; idx < 2176; idx += NTH) hT[idx] = 0.f;  // h0 = 0
  __syncthreads();

  for (int t = 0; t < Tn; ++t) {
    // ---- stage x_t (independent of peers; done before spin) ----
    if (tid < 256) {
      const int bp = tid >> 6, d = tid & 63;
      xT[d * 4 + bp] = x[((size_t)(bg * BPG + bp) * Tn + t) * Dn + d];
    }
    __syncthreads();

    // ---- gx partial dots: d = ks*2 + dd ----
    float agx[RPC][BPG];
    #pragma unroll
    for (int i = 0; i < RPC; ++i)
      #pragma unroll
      for (int b = 0; b < BPG; ++b) agx[i][b] = 0.f;
    #pragma unroll
    for (int dd = 0; dd < 2; ++dd) {
      const float4 xb = *(const float4*)&xT[(ks * 2 + dd) * 4];
      #pragma unroll
      for (int i = 0; i < RPC; ++i) {
        const float w = wxreg[i][dd];
        agx[i][0] += w * xb.x; agx[i][1] += w * xb.y;
        agx[i][2] += w * xb.z; agx[i][3] += w * xb.w;
      }
    }
    #pragma unroll
    for (int m = 1; m < KS; m <<= 1)
      #pragma unroll
      for (int i = 0; i < RPC; ++i)
        #pragma unroll
        for (int b = 0; b < BPG; ++b)
          agx[i][b] += __shfl_xor(agx[i][b], m);

    // ---- wait for peers' h_{t-1}, acquire, gather into LDS ----
    if (t > 0) {
      if (tid < NG) {
        unsigned int* fl = flags + bg * NG + tid;
        int guard = 0;
        while (__hip_atomic_load(fl, __ATOMIC_RELAXED, __HIP_MEMORY_SCOPE_AGENT) < (unsigned)t) {
          __builtin_amdgcn_s_sleep(1);
          if (++guard > (1 << 17)) break;  // bounded: wrong-result beats GPU hang
        }
      }
      __syncthreads();
      __threadfence();  // acquire: invalidate L1/L2 so hs reads are fresh
      const float4* src = (const float4*)(hs + ((size_t)(t - 1) * NBG + bg) * (NG * BPG * UG));
      for (int i4 = tid; i4 < 512; i4 += NTH) {
        const float4 v = src[i4];
        const int u0 = (i4 & 3) * 4;
        const int bp = (i4 >> 2) & 3;
        const int gp = i4 >> 4;
        const int base = gp * 68 + u0 * 4 + bp;  // = k*4 + skew + b
        hT[base] = v.x; hT[base + 4] = v.y; hT[base + 8] = v.z; hT[base + 12] = v.w;
      }
      __syncthreads();
    }

    // ---- gh partial dots: k = ks*16 + kk, weights from registers ----
    float agh[RPC][BPG];
    #pragma unroll
    for (int i = 0; i < RPC; ++i)
      #pragma unroll
      for (int b = 0; b < BPG; ++b) agh[i][b] = 0.f;
    {
      const float* hp = hT + ks * 68;  // 68 floats per 16-k section (skewed)
      #pragma unroll
      for (int kk = 0; kk < 16; ++kk) {
        const float4 hb = *(const float4*)(hp + kk * 4);  // h[k][0..3] all 4 batches
        #pragma unroll
        for (int i = 0; i < RPC; ++i) {
          const float w = wreg[i][kk];
          agh[i][0] += w * hb.x; agh[i][1] += w * hb.y;
          agh[i][2] += w * hb.z; agh[i][3] += w * hb.w;
        }
      }
    }
    #pragma unroll
    for (int m = 1; m < KS; m <<= 1)
      #pragma unroll
      for (int i = 0; i < RPC; ++i)
        #pragma unroll
        for (int b = 0; b < BPG; ++b)
          agh[i][b] += __shfl_xor(agh[i][b], m);

    if (ks == 0) {
      #pragma unroll
      for (int i = 0; i < RPC; ++i) {
        const int lr = cell * RPC + i;
        if (lr < 32) {  // r,z gates: store full pre-activation sum
          #pragma unroll
          for (int b = 0; b < BPG; ++b)
            preS[lr * 4 + b] = agx[i][b] + bihr[i] + agh[i][b] + bhhr[i];
        } else {        // n gate: keep x-part and h-part separate (r multiplies h-part)
          #pragma unroll
          for (int b = 0; b < BPG; ++b) {
            preS[lr * 4 + b] = agx[i][b] + bihr[i];
            preN[(lr - 32) * 4 + b] = agh[i][b] + bhhr[i];
          }
        }
      }
    }
    __syncthreads();

    // ---- combine + write h slice ----
    if (tid < 64) {
      const int b = tid >> 4, u = tid & 15;
      const float pr = preS[u * 4 + b];
      const float pz = preS[(16 + u) * 4 + b];
      const float px = preS[(32 + u) * 4 + b];
      const float gn = preN[u * 4 + b];
      const float r = sigmoidf_(pr);
      const float z = sigmoidf_(pz);
      const float n = tanhf(px + r * gn);
      const int j = g * UG + u;
      const float hold = hT[j * 4 + g * 4 + b];
      const float hnew = (1.f - z) * n + z * hold;
      hs[(((size_t)t * NBG + bg) * NG + g) * (BPG * UG) + b * UG + u] = hnew;
    }
    __threadfence();   // release: write back L2 so peers (other XCDs) see hs[t]
    __syncthreads();
    if (tid == 0)
      __hip_atomic_store(flags + bg * NG + g, (unsigned)(t + 1),
                         __ATOMIC_RELAXED, __HIP_MEMORY_SCOPE_AGENT);
  }
}

__global__ __launch_bounds__(256) void gru_fc(const float* __restrict__ hs,
    const float* __restrict__ w_fc, const float* __restrict__ b_fc,
    float* __restrict__ out)
{
  __shared__ float wfc[Cn * Hn];  // 20 KB
  const int tid = threadIdx.x;
  for (int i = tid; i < Cn * Hn; i += 256) wfc[i] = w_fc[i];
  __syncthreads();
  const int wave = tid >> 6, lane = tid & 63;
  const int bt = blockIdx.x * 4 + wave;        // = b*Tn + t
  const int b = bt >> 11, t = bt & (Tn - 1);
  const int bg = b >> 2, bp = b & 3;
  const float* src = hs + ((size_t)t * NBG + bg) * (NG * BPG * UG) + bp * UG;
  float acc[Cn];
  #pragma unroll
  for (int c = 0; c < Cn; ++c) acc[c] = 0.f;
  #pragma unroll
  for (int it = 0; it < 8; ++it) {
    const int j = it * 64 + lane;      // hidden unit 0..511
    const int gp = j >> 4, u = j & 15;
    const float h = src[gp * (BPG * UG) + u];
    #pragma unroll
    for (int c = 0; c < Cn; ++c) acc[c] += h * wfc[c * Hn + j];
  }
  #pragma unroll
  for (int c = 0; c < Cn; ++c) {
    #pragma unroll
    for (int m = 1; m < 64; m <<= 1) acc[c] += __shfl_xor(acc[c], m);
  }
  if (lane == 0) {
    #pragma unroll
    for (int c = 0; c < Cn; ++c) out[(size_t)bt * Cn + c] = acc[c] + b_fc[c];
  }
}

// Fallback if workspace too small: one block per batch element, zero inter-block
// communication (correct regardless of scheduling), slow but safe.
__global__ __launch_bounds__(512) void gru_fallback(
    const float* __restrict__ x, const float* __restrict__ w_ih,
    const float* __restrict__ w_hh, const float* __restrict__ b_ih,
    const float* __restrict__ b_hh, const float* __restrict__ w_fc,
    const float* __restrict__ b_fc, float* __restrict__ out)
{
  const int b = blockIdx.x;
  const int tid = threadIdx.x;  // = hidden unit
  __shared__ float hsh[Hn];
  __shared__ float xsh[Dn];
  hsh[tid] = 0.f;
  __syncthreads();
  for (int t = 0; t < Tn; ++t) {
    if (tid < Dn) xsh[tid] = x[((size_t)b * Tn + t) * Dn + tid];
    __syncthreads();
    const int u = tid;
    float gxr = 0.f, gxz = 0.f, gxn = 0.f;
    for (int d = 0; d < Dn; ++d) {
      const float xv = xsh[d];
      gxr += w_ih[(size_t)u * Dn + d] * xv;
      gxz += w_ih[(size_t)(Hn + u) * Dn + d] * xv;
      gxn += w_ih[(size_t)(2 * Hn + u) * Dn + d] * xv;
    }
    float ghr = 0.f, ghz = 0.f, ghn = 0.f;
    for (int k = 0; k < Hn; ++k) {
      const float hv = hsh[k];
      ghr += w_hh[(size_t)u * Hn + k] * hv;
      ghz += w_hh[(size_t)(Hn + u) * Hn + k] * hv;
      ghn += w_hh[(size_t)(2 * Hn + u) * Hn + k] * hv;
    }
    const float r = sigmoidf_(gxr + b_ih[u] + ghr + b_hh[u]);
    const float z = sigmoidf_(gxz + b_ih[Hn + u] + ghz + b_hh[Hn + u]);
    const float n = tanhf(gxn + b_ih[2 * Hn + u] + r * (ghn + b_hh[2 * Hn + u]));
    const float hold = hsh[u];
    __syncthreads();
    hsh[u] = (1.f - z) * n + z * hold;
    __syncthreads();
    if (tid < 320) {
      const int c = tid >> 5, l = tid & 31;
      float a = 0.f;
      for (int kk = 0; kk < 16; ++kk) {
        const int j = l * 16 + kk;
        a += hsh[j] * w_fc[c * Hn + j];
      }
      a += __shfl_xor(a, 1); a += __shfl_xor(a, 2); a += __shfl_xor(a, 4);
      a += __shfl_xor(a, 8); a += __shfl_xor(a, 16);
      if (l == 0) out[((size_t)b * Tn + t) * Cn + c] = a + b_fc[c];
    }
    __syncthreads();
  }
}

extern "C" void kernel_launch(void* const* d_in, const int* in_sizes, int n_in,
                              void* d_out, int out_size, void* d_ws, size_t ws_size,
                              hipStream_t stream) {
  const float* x    = (const float*)d_in[0];
  const float* w_ih = (const float*)d_in[1];
  const float* w_hh = (const float*)d_in[2];
  const float* b_ih = (const float*)d_in[3];
  const float* b_hh = (const float*)d_in[4];
  const float* w_fc = (const float*)d_in[5];
  const float* b_fc = (const float*)d_in[6];
  float* out = (float*)d_out;

  const size_t hs_bytes = (size_t)Tn * NBG * NG * BPG * UG * sizeof(float);  // 128 MiB
  if (ws_size >= hs_bytes + 1024) {
    float* hs = (float*)d_ws;
    unsigned int* flags = (unsigned int*)((char*)d_ws + hs_bytes);
    hipMemsetAsync(flags, 0, 1024, stream);  // monotone flags reset每launch (graph-safe)
    hipLaunchKernelGGL(gru_main, dim3(NG * NBG), dim3(NTH), 0, stream,
                       x, w_ih, w_hh, b_ih, b_hh, hs, flags);
    hipLaunchKernelGGL(gru_fc, dim3((Bsz * Tn) / 4), dim3(256), 0, stream,
                       hs, w_fc, b_fc, out);
  } else {
    hipLaunchKernelGGL(gru_fallback, dim3(Bsz), dim3(512), 0, stream,
                       x, w_ih, w_hh, b_ih, b_hh, w_fc, b_fc, out);
  }
}

// Round 2
// 14610.303 us; speedup vs baseline: 6.8779x; 6.8779x over previous
//
#include <hip/hip_runtime.h>
#include <cstdint>
#include <cstddef>

#define Bsz 32
#define Tn  2048
#define Dn  64
#define Hn  512
#define Cn  10
#define NG  32   // gate-unit groups (16 h-units each)
#define UG  16   // units per group
#define NBG 8    // batch groups
#define BPG 4    // batches per group
#define KS  32   // K-split lanes
#define RPC 4    // local gate-rows per cell (48 local rows = 3 gates x 16 units)
#define NTH 384  // 12 cells x 32 ks

__device__ __forceinline__ float sigmoidf_(float v) { return 1.f / (1.f + __expf(-v)); }

// hT layout: h[k][b] transposed with per-16-k skew: off(k,b) = k*4 + ((k>>4)<<2) + b
// max off = 511*4 + 124 + 3 = 2171 -> size 2176 floats (~8.7 KB)

__global__ __launch_bounds__(NTH) void gru_main(
    const float* __restrict__ x, const float* __restrict__ w_ih,
    const float* __restrict__ w_hh, const float* __restrict__ b_ih,
    const float* __restrict__ b_hh, float* __restrict__ hs,
    unsigned int* flags)
{
  const int g    = blockIdx.x & (NG - 1);
  const int bg   = blockIdx.x >> 5;
  const int tid  = threadIdx.x;
  const int ks   = tid & (KS - 1);
  const int cell = tid >> 5;   // 0..11

  __shared__ float hT[2176];
  __shared__ float xT[256];       // x_t transposed: [d][b]
  __shared__ float preS[48 * 4];  // r,z sums + n x-part   [local_row][b]
  __shared__ float preN[16 * 4];  // n h-part (gh_n + b_hh) [unit][b]

  // persistent per-thread weights (stay in VGPRs across all 2048 steps)
  float wreg[RPC][16];
  float wxreg[RPC][2];
  float bihr[RPC], bhhr[RPC];

  #pragma unroll
  for (int i = 0; i < RPC; ++i) {
    const int lr    = cell * RPC + i;   // 0..47 ; gate = lr>>4, unit = lr&15
    const int gamma = lr >> 4;
    const int u     = lr & 15;
    const int grow  = gamma * Hn + g * UG + u;
    const float4* wp = (const float4*)(w_hh + (size_t)grow * Hn + ks * 16);
    #pragma unroll
    for (int q = 0; q < 4; ++q) {
      const float4 v = wp[q];
      wreg[i][q * 4 + 0] = v.x; wreg[i][q * 4 + 1] = v.y;
      wreg[i][q * 4 + 2] = v.z; wreg[i][q * 4 + 3] = v.w;
    }
    wxreg[i][0] = w_ih[(size_t)grow * Dn + ks * 2 + 0];
    wxreg[i][1] = w_ih[(size_t)grow * Dn + ks * 2 + 1];
    bihr[i] = b_ih[grow];
    bhhr[i] = b_hh[grow];
  }

  for (int idx = tid; idx < 2176; idx += NTH) hT[idx] = 0.f;  // h0 = 0
  __syncthreads();

  for (int t = 0; t < Tn; ++t) {
    // ---- stage x_t (independent of peers; done before spin) ----
    if (tid < 256) {
      const int bp = tid >> 6, d = tid & 63;
      xT[d * 4 + bp] = x[((size_t)(bg * BPG + bp) * Tn + t) * Dn + d];
    }
    __syncthreads();

    // ---- gx partial dots: d = ks*2 + dd ----
    float agx[RPC][BPG];
    #pragma unroll
    for (int i = 0; i < RPC; ++i)
      #pragma unroll
      for (int b = 0; b < BPG; ++b) agx[i][b] = 0.f;
    #pragma unroll
    for (int dd = 0; dd < 2; ++dd) {
      const float4 xb = *(const float4*)&xT[(ks * 2 + dd) * 4];
      #pragma unroll
      for (int i = 0; i < RPC; ++i) {
        const float w = wxreg[i][dd];
        agx[i][0] += w * xb.x; agx[i][1] += w * xb.y;
        agx[i][2] += w * xb.z; agx[i][3] += w * xb.w;
      }
    }
    #pragma unroll
    for (int m = 1; m < KS; m <<= 1)
      #pragma unroll
      for (int i = 0; i < RPC; ++i)
        #pragma unroll
        for (int b = 0; b < BPG; ++b)
          agx[i][b] += __shfl_xor(agx[i][b], m);

    // ---- wait for peers' h_{t-1}: device-scope (sc1) loads, NO cache fences ----
    if (t > 0) {
      if (tid < NG) {
        unsigned int* fl = flags + bg * NG + tid;
        int guard = 0;
        while (__hip_atomic_load(fl, __ATOMIC_RELAXED, __HIP_MEMORY_SCOPE_AGENT) < (unsigned)t) {
          __builtin_amdgcn_s_sleep(1);
          if (++guard > (1 << 20)) break;  // bounded: wrong-result beats GPU hang
        }
      }
      __syncthreads();
      // gather h_{t-1} (8 KB) with device-scope dword loads (bypass L1/L2 -> MALL,
      // coherent across XCDs; compiler pipelines + inserts waitcnts)
      const float* src = hs + ((size_t)(t - 1) * NBG + bg) * (NG * BPG * UG);
      #pragma unroll
      for (int r = 0; r < 6; ++r) {
        const int j = r * NTH + tid;           // 6*384 = 2304 >= 2048
        if (j < 2048) {
          const float v = __hip_atomic_load(src + j, __ATOMIC_RELAXED, __HIP_MEMORY_SCOPE_AGENT);
          // j = g*64 + b*16 + u ; k = (j>>6)*16 + (j&15); off = k*4 + ((k>>4)<<2) + b
          const int off = (j >> 6) * 68 + (j & 15) * 4 + ((j >> 4) & 3);
          hT[off] = v;
        }
      }
      __syncthreads();
    }

    // ---- gh partial dots: k = ks*16 + kk, weights from registers ----
    float agh[RPC][BPG];
    #pragma unroll
    for (int i = 0; i < RPC; ++i)
      #pragma unroll
      for (int b = 0; b < BPG; ++b) agh[i][b] = 0.f;
    {
      const float* hp = hT + ks * 68;  // 68 floats per 16-k section (skewed)
      #pragma unroll
      for (int kk = 0; kk < 16; ++kk) {
        const float4 hb = *(const float4*)(hp + kk * 4);  // h[k][0..3] all 4 batches
        #pragma unroll
        for (int i = 0; i < RPC; ++i) {
          const float w = wreg[i][kk];
          agh[i][0] += w * hb.x; agh[i][1] += w * hb.y;
          agh[i][2] += w * hb.z; agh[i][3] += w * hb.w;
        }
      }
    }
    #pragma unroll
    for (int m = 1; m < KS; m <<= 1)
      #pragma unroll
      for (int i = 0; i < RPC; ++i)
        #pragma unroll
        for (int b = 0; b < BPG; ++b)
          agh[i][b] += __shfl_xor(agh[i][b], m);

    if (ks == 0) {
      #pragma unroll
      for (int i = 0; i < RPC; ++i) {
        const int lr = cell * RPC + i;
        if (lr < 32) {  // r,z gates: store full pre-activation sum
          #pragma unroll
          for (int b = 0; b < BPG; ++b)
            preS[lr * 4 + b] = agx[i][b] + bihr[i] + agh[i][b] + bhhr[i];
        } else {        // n gate: keep x-part and h-part separate (r multiplies h-part)
          #pragma unroll
          for (int b = 0; b < BPG; ++b) {
            preS[lr * 4 + b] = agx[i][b] + bihr[i];
            preN[(lr - 32) * 4 + b] = agh[i][b] + bhhr[i];
          }
        }
      }
    }
    __syncthreads();

    // ---- combine + write h slice (device-scope store: write-through to MALL) ----
    if (tid < 64) {
      const int b = tid >> 4, u = tid & 15;
      const float pr = preS[u * 4 + b];
      const float pz = preS[(16 + u) * 4 + b];
      const float px = preS[(32 + u) * 4 + b];
      const float gn = preN[u * 4 + b];
      const float r = sigmoidf_(pr);
      const float z = sigmoidf_(pz);
      const float n = tanhf(px + r * gn);
      const int j = g * UG + u;
      const float hold = hT[j * 4 + g * 4 + b];
      const float hnew = (1.f - z) * n + z * hold;
      __hip_atomic_store(
          &hs[(((size_t)t * NBG + bg) * NG + g) * (BPG * UG) + b * UG + u], hnew,
          __ATOMIC_RELAXED, __HIP_MEMORY_SCOPE_AGENT);
    }
    // __syncthreads drains vmcnt(0) for ALL threads before the barrier releases,
    // so the flag store below is ordered after every h store (release for free).
    __syncthreads();
    if (tid == 0)
      __hip_atomic_store(flags + bg * NG + g, (unsigned)(t + 1),
                         __ATOMIC_RELAXED, __HIP_MEMORY_SCOPE_AGENT);
  }
}

__global__ __launch_bounds__(256) void gru_fc(const float* __restrict__ hs,
    const float* __restrict__ w_fc, const float* __restrict__ b_fc,
    float* __restrict__ out)
{
  __shared__ float wfc[Cn * Hn];  // 20 KB
  const int tid = threadIdx.x;
  for (int i = tid; i < Cn * Hn; i += 256) wfc[i] = w_fc[i];
  __syncthreads();
  const int wave = tid >> 6, lane = tid & 63;
  const int bt = blockIdx.x * 4 + wave;        // = b*Tn + t
  const int b = bt >> 11, t = bt & (Tn - 1);
  const int bg = b >> 2, bp = b & 3;
  const float* src = hs + ((size_t)t * NBG + bg) * (NG * BPG * UG) + bp * UG;
  float acc[Cn];
  #pragma unroll
  for (int c = 0; c < Cn; ++c) acc[c] = 0.f;
  #pragma unroll
  for (int it = 0; it < 8; ++it) {
    const int j = it * 64 + lane;      // hidden unit 0..511
    const int gp = j >> 4, u = j & 15;
    const float h = src[gp * (BPG * UG) + u];
    #pragma unroll
    for (int c = 0; c < Cn; ++c) acc[c] += h * wfc[c * Hn + j];
  }
  #pragma unroll
  for (int c = 0; c < Cn; ++c) {
    #pragma unroll
    for (int m = 1; m < 64; m <<= 1) acc[c] += __shfl_xor(acc[c], m);
  }
  if (lane == 0) {
    #pragma unroll
    for (int c = 0; c < Cn; ++c) out[(size_t)bt * Cn + c] = acc[c] + b_fc[c];
  }
}

// Fallback if workspace too small: one block per batch element, zero inter-block
// communication (correct regardless of scheduling), slow but safe.
__global__ __launch_bounds__(512) void gru_fallback(
    const float* __restrict__ x, const float* __restrict__ w_ih,
    const float* __restrict__ w_hh, const float* __restrict__ b_ih,
    const float* __restrict__ b_hh, const float* __restrict__ w_fc,
    const float* __restrict__ b_fc, float* __restrict__ out)
{
  const int b = blockIdx.x;
  const int tid = threadIdx.x;  // = hidden unit
  __shared__ float hsh[Hn];
  __shared__ float xsh[Dn];
  hsh[tid] = 0.f;
  __syncthreads();
  for (int t = 0; t < Tn; ++t) {
    if (tid < Dn) xsh[tid] = x[((size_t)b * Tn + t) * Dn + tid];
    __syncthreads();
    const int u = tid;
    float gxr = 0.f, gxz = 0.f, gxn = 0.f;
    for (int d = 0; d < Dn; ++d) {
      const float xv = xsh[d];
      gxr += w_ih[(size_t)u * Dn + d] * xv;
      gxz += w_ih[(size_t)(Hn + u) * Dn + d] * xv;
      gxn += w_ih[(size_t)(2 * Hn + u) * Dn + d] * xv;
    }
    float ghr = 0.f, ghz = 0.f, ghn = 0.f;
    for (int k = 0; k < Hn; ++k) {
      const float hv = hsh[k];
      ghr += w_hh[(size_t)u * Hn + k] * hv;
      ghz += w_hh[(size_t)(Hn + u) * Hn + k] * hv;
      ghn += w_hh[(size_t)(2 * Hn + u) * Hn + k] * hv;
    }
    const float r = sigmoidf_(gxr + b_ih[u] + ghr + b_hh[u]);
    const float z = sigmoidf_(gxz + b_ih[Hn + u] + ghz + b_hh[Hn + u]);
    const float n = tanhf(gxn + b_ih[2 * Hn + u] + r * (ghn + b_hh[2 * Hn + u]));
    const float hold = hsh[u];
    __syncthreads();
    hsh[u] = (1.f - z) * n + z * hold;
    __syncthreads();
    if (tid < 320) {
      const int c = tid >> 5, l = tid & 31;
      float a = 0.f;
      for (int kk = 0; kk < 16; ++kk) {
        const int j = l * 16 + kk;
        a += hsh[j] * w_fc[c * Hn + j];
      }
      a += __shfl_xor(a, 1); a += __shfl_xor(a, 2); a += __shfl_xor(a, 4);
      a += __shfl_xor(a, 8); a += __shfl_xor(a, 16);
      if (l == 0) out[((size_t)b * Tn + t) * Cn + c] = a + b_fc[c];
    }
    __syncthreads();
  }
}

extern "C" void kernel_launch(void* const* d_in, const int* in_sizes, int n_in,
                              void* d_out, int out_size, void* d_ws, size_t ws_size,
                              hipStream_t stream) {
  const float* x    = (const float*)d_in[0];
  const float* w_ih = (const float*)d_in[1];
  const float* w_hh = (const float*)d_in[2];
  const float* b_ih = (const float*)d_in[3];
  const float* b_hh = (const float*)d_in[4];
  const float* w_fc = (const float*)d_in[5];
  const float* b_fc = (const float*)d_in[6];
  float* out = (float*)d_out;

  const size_t hs_bytes = (size_t)Tn * NBG * NG * BPG * UG * sizeof(float);  // 128 MiB
  if (ws_size >= hs_bytes + 1024) {
    float* hs = (float*)d_ws;
    unsigned int* flags = (unsigned int*)((char*)d_ws + hs_bytes);
    hipMemsetAsync(flags, 0, 1024, stream);  // monotone flags reset per launch (graph-safe)
    hipLaunchKernelGGL(gru_main, dim3(NG * NBG), dim3(NTH), 0, stream,
                       x, w_ih, w_hh, b_ih, b_hh, hs, flags);
    hipLaunchKernelGGL(gru_fc, dim3((Bsz * Tn) / 4), dim3(256), 0, stream,
                       hs, w_fc, b_fc, out);
  } else {
    hipLaunchKernelGGL(gru_fallback, dim3(Bsz), dim3(512), 0, stream,
                       x, w_ih, w_hh, b_ih, b_hh, w_fc, b_fc, out);
  }
}

// Round 3
// 14066.525 us; speedup vs baseline: 7.1438x; 1.0387x over previous
//
#include <hip/hip_runtime.h>
#include <cstdint>
#include <cstddef>

#define Bsz 32
#define Tn  2048
#define Dn  64
#define Hn  512
#define Cn  10
#define NG  32   // gate-unit groups (16 h-units each)
#define UG  16   // units per group
#define NBG 8    // batch groups
#define BPG 4    // batches per group
#define KS  32   // K-split lanes
#define RPC 4    // local gate-rows per cell
#define NTH 384  // 12 cells x 32 ks
#define XW  2048 // exchange words per (parity,bg) = NG*BPG*UG

__device__ __forceinline__ float sigmoidf_(float v) { return 1.f / (1.f + __expf(-v)); }

// hT layout: h[k][b] transposed with per-16-k skew: off(k,b) = k*4 + ((k>>4)<<2) + b
// size 2176 floats (~8.7 KB)

__global__ __launch_bounds__(NTH) void gru_main(
    const float* __restrict__ x, const float* __restrict__ w_ih,
    const float* __restrict__ w_hh, const float* __restrict__ b_ih,
    const float* __restrict__ b_hh, float* __restrict__ hs,
    unsigned long long* __restrict__ xch)   // [2][NBG][XW] tagged ring
{
  const int g    = blockIdx.x & (NG - 1);
  const int bg   = blockIdx.x >> 5;
  const int tid  = threadIdx.x;
  const int ks   = tid & (KS - 1);
  const int cell = tid >> 5;   // 0..11

  __shared__ float hT[2176];
  __shared__ float xT[2][256];    // double-buffered x_t transposed: [d][b]
  __shared__ float preS[48 * 4];
  __shared__ float preN[16 * 4];

  float wreg[RPC][16], wxreg[RPC][2], bihr[RPC], bhhr[RPC];
  #pragma unroll
  for (int i = 0; i < RPC; ++i) {
    const int lr    = cell * RPC + i;
    const int gamma = lr >> 4;
    const int u     = lr & 15;
    const int grow  = gamma * Hn + g * UG + u;
    const float4* wp = (const float4*)(w_hh + (size_t)grow * Hn + ks * 16);
    #pragma unroll
    for (int q = 0; q < 4; ++q) {
      const float4 v = wp[q];
      wreg[i][q * 4 + 0] = v.x; wreg[i][q * 4 + 1] = v.y;
      wreg[i][q * 4 + 2] = v.z; wreg[i][q * 4 + 3] = v.w;
    }
    wxreg[i][0] = w_ih[(size_t)grow * Dn + ks * 2 + 0];
    wxreg[i][1] = w_ih[(size_t)grow * Dn + ks * 2 + 1];
    bihr[i] = b_ih[grow];
    bhhr[i] = b_hh[grow];
  }

  unsigned long long* const sl0 = xch + (size_t)bg * XW;          // parity 0
  unsigned long long* const sl1 = xch + (size_t)(NBG + bg) * XW;  // parity 1

  for (int idx = tid; idx < 2176; idx += NTH) hT[idx] = 0.f;  // h0 = 0
  if (tid < 256) {
    const int bp = tid >> 6, d = tid & 63;
    xT[0][d * 4 + bp] = x[((size_t)(bg * BPG + bp) * Tn + 0) * Dn + d];
  }
  float hold = 0.f;   // own h_{t-1}[unit] lives in a register (tid<64)
  __syncthreads();

  for (int t = 0; t < Tn; ++t) {
    const int p = t & 1;

    // (1) prefetch x_{t+1} into regs (latency hides under the poll below)
    float xpre = 0.f;
    if (tid < 256) {
      const int bp = tid >> 6, d = tid & 63;
      const int tn = (t + 1 < Tn) ? (t + 1) : t;
      xpre = x[((size_t)(bg * BPG + bp) * Tn + tn) * Dn + d];
    }

    // (2) gx partials + reduce (runs while peers finish step t-1)
    float agx[RPC][BPG];
    #pragma unroll
    for (int i = 0; i < RPC; ++i) { agx[i][0]=0.f; agx[i][1]=0.f; agx[i][2]=0.f; agx[i][3]=0.f; }
    #pragma unroll
    for (int dd = 0; dd < 2; ++dd) {
      const float4 xb = *(const float4*)&xT[p][(ks * 2 + dd) * 4];
      #pragma unroll
      for (int i = 0; i < RPC; ++i) {
        const float w = wxreg[i][dd];
        agx[i][0] += w * xb.x; agx[i][1] += w * xb.y;
        agx[i][2] += w * xb.z; agx[i][3] += w * xb.w;
      }
    }
    #pragma unroll
    for (int m = 1; m < KS; m <<= 1)
      #pragma unroll
      for (int i = 0; i < RPC; ++i)
        #pragma unroll
        for (int b = 0; b < BPG; ++b)
          agx[i][b] += __shfl_xor(agx[i][b], m);

    // (3) tag-poll gather of h_{t-1}: the gather IS the synchronization.
    if (t > 0) {
      const unsigned long long* src = p ? sl0 : sl1;   // parity (t-1)&1
      const unsigned long long want = (unsigned long long)t;  // tag = (t-1)+1
      unsigned long long v0=0,v1=0,v2=0,v3=0,v4=0,v5=0;
      bool o0=false,o1=false,o2=false,o3=false,o4=false;
      bool o5 = (5 * NTH + tid >= XW);
      int guard = 0;
      for (;;) {
        if (!o0){ unsigned long long w=__hip_atomic_load(src+0*NTH+tid,__ATOMIC_RELAXED,__HIP_MEMORY_SCOPE_AGENT); if((w>>32)==want){v0=w;o0=true;} }
        if (!o1){ unsigned long long w=__hip_atomic_load(src+1*NTH+tid,__ATOMIC_RELAXED,__HIP_MEMORY_SCOPE_AGENT); if((w>>32)==want){v1=w;o1=true;} }
        if (!o2){ unsigned long long w=__hip_atomic_load(src+2*NTH+tid,__ATOMIC_RELAXED,__HIP_MEMORY_SCOPE_AGENT); if((w>>32)==want){v2=w;o2=true;} }
        if (!o3){ unsigned long long w=__hip_atomic_load(src+3*NTH+tid,__ATOMIC_RELAXED,__HIP_MEMORY_SCOPE_AGENT); if((w>>32)==want){v3=w;o3=true;} }
        if (!o4){ unsigned long long w=__hip_atomic_load(src+4*NTH+tid,__ATOMIC_RELAXED,__HIP_MEMORY_SCOPE_AGENT); if((w>>32)==want){v4=w;o4=true;} }
        if (!o5){ unsigned long long w=__hip_atomic_load(src+5*NTH+tid,__ATOMIC_RELAXED,__HIP_MEMORY_SCOPE_AGENT); if((w>>32)==want){v5=w;o5=true;} }
        if (o0 && o1 && o2 && o3 && o4 && o5) break;
        if (++guard > (1 << 18)) break;  // bounded: wrong result beats hang
      }
      union { unsigned u; float f; } c;
      int j;
      j = 0*NTH+tid; c.u = (unsigned)v0; hT[(j>>6)*68 + (j&15)*4 + ((j>>4)&3)] = c.f;
      j = 1*NTH+tid; c.u = (unsigned)v1; hT[(j>>6)*68 + (j&15)*4 + ((j>>4)&3)] = c.f;
      j = 2*NTH+tid; c.u = (unsigned)v2; hT[(j>>6)*68 + (j&15)*4 + ((j>>4)&3)] = c.f;
      j = 3*NTH+tid; c.u = (unsigned)v3; hT[(j>>6)*68 + (j&15)*4 + ((j>>4)&3)] = c.f;
      j = 4*NTH+tid; c.u = (unsigned)v4; hT[(j>>6)*68 + (j&15)*4 + ((j>>4)&3)] = c.f;
      j = 5*NTH+tid; c.u = (unsigned)v5; if (j < XW) hT[(j>>6)*68 + (j&15)*4 + ((j>>4)&3)] = c.f;
    }

    // (4) stage x_{t+1} into the other xT buffer (load long since arrived)
    if (tid < 256) { const int bp = tid >> 6, d = tid & 63; xT[p ^ 1][d * 4 + bp] = xpre; }
    __syncthreads();   // barrier B: hT + xT ready

    // (6) gh partials + reduce (weights in VGPRs, h from LDS broadcast)
    float agh[RPC][BPG];
    #pragma unroll
    for (int i = 0; i < RPC; ++i) { agh[i][0]=0.f; agh[i][1]=0.f; agh[i][2]=0.f; agh[i][3]=0.f; }
    {
      const float* hp = hT + ks * 68;
      #pragma unroll
      for (int kk = 0; kk < 16; ++kk) {
        const float4 hb = *(const float4*)(hp + kk * 4);
        #pragma unroll
        for (int i = 0; i < RPC; ++i) {
          const float w = wreg[i][kk];
          agh[i][0] += w * hb.x; agh[i][1] += w * hb.y;
          agh[i][2] += w * hb.z; agh[i][3] += w * hb.w;
        }
      }
    }
    #pragma unroll
    for (int m = 1; m < KS; m <<= 1)
      #pragma unroll
      for (int i = 0; i < RPC; ++i)
        #pragma unroll
        for (int b = 0; b < BPG; ++b)
          agh[i][b] += __shfl_xor(agh[i][b], m);

    if (ks == 0) {
      #pragma unroll
      for (int i = 0; i < RPC; ++i) {
        const int lr = cell * RPC + i;
        if (lr < 32) {
          #pragma unroll
          for (int b = 0; b < BPG; ++b)
            preS[lr * 4 + b] = agx[i][b] + bihr[i] + agh[i][b] + bhhr[i];
        } else {
          #pragma unroll
          for (int b = 0; b < BPG; ++b) {
            preS[lr * 4 + b] = agx[i][b] + bihr[i];
            preN[(lr - 32) * 4 + b] = agh[i][b] + bhhr[i];
          }
        }
      }
    }
    __syncthreads();   // barrier C: preS/preN ready

    // (9) combine + tagged 8B store (data+tag indivisible -> no fences/flags)
    if (tid < 64) {
      const int b = tid >> 4, u = tid & 15;
      const float r = sigmoidf_(preS[u * 4 + b]);
      const float z = sigmoidf_(preS[(16 + u) * 4 + b]);
      const float n = tanhf(preS[(32 + u) * 4 + b] + r * preN[u * 4 + b]);
      const float hnew = (1.f - z) * n + z * hold;
      hold = hnew;
      hs[((size_t)t * NBG + bg) * XW + g * 64 + tid] = hnew;  // plain store for FC
      union { float f; unsigned u32; } cu; cu.f = hnew;
      const unsigned long long w = ((unsigned long long)(t + 1) << 32) | cu.u32;
      unsigned long long* dst = p ? sl1 : sl0;
      __hip_atomic_store(dst + g * 64 + tid, w, __ATOMIC_RELAXED, __HIP_MEMORY_SCOPE_AGENT);
    }
    // no barrier here: next-step hT writes happen after C; preS rewrite after B'
  }
}

__global__ __launch_bounds__(256) void gru_fc(const float* __restrict__ hs,
    const float* __restrict__ w_fc, const float* __restrict__ b_fc,
    float* __restrict__ out)
{
  __shared__ float wfc[Cn * Hn];  // 20 KB
  const int tid = threadIdx.x;
  for (int i = tid; i < Cn * Hn; i += 256) wfc[i] = w_fc[i];
  __syncthreads();
  const int wave = tid >> 6, lane = tid & 63;
  const int bt = blockIdx.x * 4 + wave;        // = b*Tn + t
  const int b = bt >> 11, t = bt & (Tn - 1);
  const int bg = b >> 2, bp = b & 3;
  const float* src = hs + ((size_t)t * NBG + bg) * (NG * BPG * UG) + bp * UG;
  float acc[Cn];
  #pragma unroll
  for (int c = 0; c < Cn; ++c) acc[c] = 0.f;
  #pragma unroll
  for (int it = 0; it < 8; ++it) {
    const int j = it * 64 + lane;
    const int gp = j >> 4, u = j & 15;
    const float h = src[gp * (BPG * UG) + u];
    #pragma unroll
    for (int c = 0; c < Cn; ++c) acc[c] += h * wfc[c * Hn + j];
  }
  #pragma unroll
  for (int c = 0; c < Cn; ++c) {
    #pragma unroll
    for (int m = 1; m < 64; m <<= 1) acc[c] += __shfl_xor(acc[c], m);
  }
  if (lane == 0) {
    #pragma unroll
    for (int c = 0; c < Cn; ++c) out[(size_t)bt * Cn + c] = acc[c] + b_fc[c];
  }
}

// Fallback if workspace too small: one block per batch, no inter-block comms.
__global__ __launch_bounds__(512) void gru_fallback(
    const float* __restrict__ x, const float* __restrict__ w_ih,
    const float* __restrict__ w_hh, const float* __restrict__ b_ih,
    const float* __restrict__ b_hh, const float* __restrict__ w_fc,
    const float* __restrict__ b_fc, float* __restrict__ out)
{
  const int b = blockIdx.x;
  const int tid = threadIdx.x;
  __shared__ float hsh[Hn];
  __shared__ float xsh[Dn];
  hsh[tid] = 0.f;
  __syncthreads();
  for (int t = 0; t < Tn; ++t) {
    if (tid < Dn) xsh[tid] = x[((size_t)b * Tn + t) * Dn + tid];
    __syncthreads();
    const int u = tid;
    float gxr = 0.f, gxz = 0.f, gxn = 0.f;
    for (int d = 0; d < Dn; ++d) {
      const float xv = xsh[d];
      gxr += w_ih[(size_t)u * Dn + d] * xv;
      gxz += w_ih[(size_t)(Hn + u) * Dn + d] * xv;
      gxn += w_ih[(size_t)(2 * Hn + u) * Dn + d] * xv;
    }
    float ghr = 0.f, ghz = 0.f, ghn = 0.f;
    for (int k = 0; k < Hn; ++k) {
      const float hv = hsh[k];
      ghr += w_hh[(size_t)u * Hn + k] * hv;
      ghz += w_hh[(size_t)(Hn + u) * Hn + k] * hv;
      ghn += w_hh[(size_t)(2 * Hn + u) * Hn + k] * hv;
    }
    const float r = sigmoidf_(gxr + b_ih[u] + ghr + b_hh[u]);
    const float z = sigmoidf_(gxz + b_ih[Hn + u] + ghz + b_hh[Hn + u]);
    const float n = tanhf(gxn + b_ih[2 * Hn + u] + r * (ghn + b_hh[2 * Hn + u]));
    const float hold = hsh[u];
    __syncthreads();
    hsh[u] = (1.f - z) * n + z * hold;
    __syncthreads();
    if (tid < 320) {
      const int c = tid >> 5, l = tid & 31;
      float a = 0.f;
      for (int kk = 0; kk < 16; ++kk) {
        const int j = l * 16 + kk;
        a += hsh[j] * w_fc[c * Hn + j];
      }
      a += __shfl_xor(a, 1); a += __shfl_xor(a, 2); a += __shfl_xor(a, 4);
      a += __shfl_xor(a, 8); a += __shfl_xor(a, 16);
      if (l == 0) out[((size_t)b * Tn + t) * Cn + c] = a + b_fc[c];
    }
    __syncthreads();
  }
}

extern "C" void kernel_launch(void* const* d_in, const int* in_sizes, int n_in,
                              void* d_out, int out_size, void* d_ws, size_t ws_size,
                              hipStream_t stream) {
  const float* x    = (const float*)d_in[0];
  const float* w_ih = (const float*)d_in[1];
  const float* w_hh = (const float*)d_in[2];
  const float* b_ih = (const float*)d_in[3];
  const float* b_hh = (const float*)d_in[4];
  const float* w_fc = (const float*)d_in[5];
  const float* b_fc = (const float*)d_in[6];
  float* out = (float*)d_out;

  const size_t hs_bytes  = (size_t)Tn * NBG * XW * sizeof(float);       // 128 MiB
  const size_t xch_bytes = (size_t)2 * NBG * XW * sizeof(unsigned long long);  // 256 KiB

  if (ws_size >= hs_bytes) {
    float* hs = (float*)d_ws;
    // exchange ring lives in d_out (2.6 MB); gru_fc fully overwrites it after.
    unsigned long long* xchg = (unsigned long long*)d_out;
    hipMemsetAsync(xchg, 0, xch_bytes, stream);  // clear tags each launch (graph-safe)
    hipLaunchKernelGGL(gru_main, dim3(NG * NBG), dim3(NTH), 0, stream,
                       x, w_ih, w_hh, b_ih, b_hh, hs, xchg);
    hipLaunchKernelGGL(gru_fc, dim3((Bsz * Tn) / 4), dim3(256), 0, stream,
                       hs, w_fc, b_fc, out);
  } else {
    hipLaunchKernelGGL(gru_fallback, dim3(Bsz), dim3(512), 0, stream,
                       x, w_ih, w_hh, b_ih, b_hh, w_fc, b_fc, out);
  }
}

// Round 4
// 12350.528 us; speedup vs baseline: 8.1363x; 1.1389x over previous
//
#include <hip/hip_runtime.h>
#include <cstdint>
#include <cstddef>

#define Bsz 32
#define Tn  2048
#define Dn  64
#define Hn  512
#define Cn  10
#define NG  32   // gate-unit groups (16 h-units each)
#define UG  16   // units per group
#define NBG 8    // batch groups
#define BPG 4    // batches per group
#define KS  32   // K-split lanes
#define NTH 512  // 16 cells (one per unit) x 32 ks
#define XW  2048 // exchange words per (parity,bg) = NG*BPG*UG

__device__ __forceinline__ float sigmoidf_(float v) { return 1.f / (1.f + __expf(-v)); }
__device__ __forceinline__ float tanhf_(float v) {
  const float c = fminf(fmaxf(v, -15.f), 15.f);
  const float e = __expf(-2.f * c);
  return (1.f - e) / (1.f + e);
}

// hT layout: h[k][b] skewed: off = k*4 + ((k>>4)<<2) + b ; word j = g*64+u*4+b
// -> off = j + 4*(j>>6). size 2176 floats per buffer.

__global__ __launch_bounds__(NTH) void gru_main(
    const float* __restrict__ x, const float* __restrict__ w_ih,
    const float* __restrict__ w_hh, const float* __restrict__ b_ih,
    const float* __restrict__ b_hh, float* __restrict__ hs,
    unsigned long long* __restrict__ xch)   // [2][NBG][XW] tagged ring
{
  const int g   = blockIdx.x & (NG - 1);
  const int bg  = blockIdx.x >> 5;
  const int tid = threadIdx.x;
  const int ks  = tid & (KS - 1);
  const int u   = tid >> 5;   // cell 0..15 == unit within group

  __shared__ float hTb[2][2176];
  __shared__ float xT[2][256];    // x_t transposed: [d][b], double buffered

  // persistent per-thread weights (VGPRs for all 2048 steps)
  float wreg[3][16];   // w_hh rows (r,z,n) of unit u, k = ks*16..+15
  float wxreg[3][2];   // w_ih rows, d = ks*2, ks*2+1
  float brz[2];        // b_ih+b_hh for r,z
  float bnx, bnh;      // b_ih[n], b_hh[n]
  #pragma unroll
  for (int i = 0; i < 3; ++i) {
    const int grow = i * Hn + g * UG + u;
    const float4* wp = (const float4*)(w_hh + (size_t)grow * Hn + ks * 16);
    #pragma unroll
    for (int q = 0; q < 4; ++q) {
      const float4 v = wp[q];
      wreg[i][q * 4 + 0] = v.x; wreg[i][q * 4 + 1] = v.y;
      wreg[i][q * 4 + 2] = v.z; wreg[i][q * 4 + 3] = v.w;
    }
    wxreg[i][0] = w_ih[(size_t)grow * Dn + ks * 2 + 0];
    wxreg[i][1] = w_ih[(size_t)grow * Dn + ks * 2 + 1];
    if (i < 2) brz[i] = b_ih[grow] + b_hh[grow];
    else { bnx = b_ih[grow]; bnh = b_hh[grow]; }
  }

  unsigned long long* const sl0 = xch + (size_t)bg * XW;          // parity 0
  unsigned long long* const sl1 = xch + (size_t)(NBG + bg) * XW;  // parity 1

  for (int idx = tid; idx < 2176; idx += NTH) hTb[0][idx] = 0.f;  // h0 = 0
  if (tid < 256) {
    const int bp = tid >> 6, d = tid & 63;
    xT[0][d * 4 + bp] = x[((size_t)(bg * BPG + bp) * Tn + 0) * Dn + d];
  }
  float hold[BPG] = {0.f, 0.f, 0.f, 0.f};   // own h_{t-1}[u][b] (ks==0 threads)
  __syncthreads();

  for (int t = 0; t < Tn; ++t) {
    const int tp = t & 1;
    float* const hT = hTb[tp];

    // (1) prefetch x_{t+1} (latency hides under poll)
    float xpre = 0.f;
    if (tid < 256) {
      const int bp = tid >> 6, d = tid & 63;
      const int tn = (t + 1 < Tn) ? (t + 1) : t;
      xpre = x[((size_t)(bg * BPG + bp) * Tn + tn) * Dn + d];
    }

    // (2) gx partials -> accumulator init (merged reduce later)
    // groups: 0=r(gx+gh), 1=z(gx+gh), 2=n x-part, 3=n h-part
    float acc[4][BPG];
    #pragma unroll
    for (int b = 0; b < BPG; ++b) { acc[0][b]=0.f; acc[1][b]=0.f; acc[2][b]=0.f; acc[3][b]=0.f; }
    #pragma unroll
    for (int dd = 0; dd < 2; ++dd) {
      const float4 xb = *(const float4*)&xT[tp][(ks * 2 + dd) * 4];
      #pragma unroll
      for (int i = 0; i < 3; ++i) {
        const float w = wxreg[i][dd];
        const int gidx = (i == 2) ? 2 : i;
        acc[gidx][0] += w * xb.x; acc[gidx][1] += w * xb.y;
        acc[gidx][2] += w * xb.z; acc[gidx][3] += w * xb.w;
      }
    }

    // (3) batched tag-poll gather of h_{t-1} (4 words/thread, single test)
    if (t > 0) {
      const unsigned long long* src = tp ? sl0 : sl1;   // parity (t-1)&1
      const unsigned long long want = (unsigned long long)t;
      unsigned long long v0, v1, v2, v3;
      int guard = 0;
      for (;;) {
        v0 = __hip_atomic_load(src + tid,        __ATOMIC_RELAXED, __HIP_MEMORY_SCOPE_AGENT);
        v1 = __hip_atomic_load(src + 512 + tid,  __ATOMIC_RELAXED, __HIP_MEMORY_SCOPE_AGENT);
        v2 = __hip_atomic_load(src + 1024 + tid, __ATOMIC_RELAXED, __HIP_MEMORY_SCOPE_AGENT);
        v3 = __hip_atomic_load(src + 1536 + tid, __ATOMIC_RELAXED, __HIP_MEMORY_SCOPE_AGENT);
        const bool ok = ((v0 >> 32) == want) & ((v1 >> 32) == want) &
                        ((v2 >> 32) == want) & ((v3 >> 32) == want);
        if (ok) break;
        if (++guard > (1 << 18)) break;        // bounded: wrong result beats hang
        if (guard > 4) __builtin_amdgcn_s_sleep(1);
      }
      union { unsigned u32; float f; } c;
      const int off0 = tid + 4 * (tid >> 6);   // off = j + 4*(j>>6)
      c.u32 = (unsigned)v0; hT[off0]        = c.f;
      c.u32 = (unsigned)v1; hT[off0 + 544]  = c.f;   // 512 + 4*8
      c.u32 = (unsigned)v2; hT[off0 + 1088] = c.f;
      c.u32 = (unsigned)v3; hT[off0 + 1632] = c.f;
    }

    // (4) stage x_{t+1}
    if (tid < 256) { const int bp = tid >> 6, d = tid & 63; xT[tp ^ 1][d * 4 + bp] = xpre; }
    __syncthreads();   // the ONLY barrier per step

    // (5) gh partials (weights in VGPRs, h broadcast from LDS)
    {
      const float* hp = hT + ks * 68;
      #pragma unroll
      for (int kk = 0; kk < 16; ++kk) {
        const float4 hb = *(const float4*)(hp + kk * 4);
        const float w0 = wreg[0][kk], w1 = wreg[1][kk], w2 = wreg[2][kk];
        acc[0][0] += w0 * hb.x; acc[0][1] += w0 * hb.y; acc[0][2] += w0 * hb.z; acc[0][3] += w0 * hb.w;
        acc[1][0] += w1 * hb.x; acc[1][1] += w1 * hb.y; acc[1][2] += w1 * hb.z; acc[1][3] += w1 * hb.w;
        acc[3][0] += w2 * hb.x; acc[3][1] += w2 * hb.y; acc[3][2] += w2 * hb.z; acc[3][3] += w2 * hb.w;
      }
    }

    // (6) single merged butterfly reduce over the 32 ks lanes
    #pragma unroll
    for (int m = 1; m < KS; m <<= 1)
      #pragma unroll
      for (int i = 0; i < 4; ++i)
        #pragma unroll
        for (int b = 0; b < BPG; ++b)
          acc[i][b] += __shfl_xor(acc[i][b], m);

    // (7) combine locally on ks==0 lanes; publish FIRST, hs store after
    if (ks == 0) {
      unsigned long long wpub[BPG];
      float4 hv;
      float* hvp = &hv.x;
      #pragma unroll
      for (int b = 0; b < BPG; ++b) {
        const float r = sigmoidf_(acc[0][b] + brz[0]);
        const float z = sigmoidf_(acc[1][b] + brz[1]);
        const float n = tanhf_(acc[2][b] + bnx + r * (acc[3][b] + bnh));
        const float h = (1.f - z) * n + z * hold[b];
        hold[b] = h;
        hvp[b] = h;
        union { float f; unsigned u32; } cu; cu.f = h;
        wpub[b] = ((unsigned long long)(t + 1) << 32) | cu.u32;
      }
      unsigned long long* dst = (tp ? sl1 : sl0) + (g << 6) + (u << 2);
      #pragma unroll
      for (int b = 0; b < BPG; ++b)
        __hip_atomic_store(dst + b, wpub[b], __ATOMIC_RELAXED, __HIP_MEMORY_SCOPE_AGENT);
      *(float4*)(hs + ((size_t)t * NBG + bg) * XW + (g << 6) + (u << 2)) = hv;
    }
  }
}

__global__ __launch_bounds__(256) void gru_fc(const float* __restrict__ hs,
    const float* __restrict__ w_fc, const float* __restrict__ b_fc,
    float* __restrict__ out)
{
  __shared__ float wfc[Cn * Hn];  // 20 KB
  const int tid = threadIdx.x;
  for (int i = tid; i < Cn * Hn; i += 256) wfc[i] = w_fc[i];
  __syncthreads();
  const int wave = tid >> 6, lane = tid & 63;
  const int bt = blockIdx.x * 4 + wave;        // = b*Tn + t
  const int b = bt >> 11, t = bt & (Tn - 1);
  const int bg = b >> 2, bp = b & 3;
  const float* src = hs + ((size_t)t * NBG + bg) * XW;
  float acc[Cn];
  #pragma unroll
  for (int c = 0; c < Cn; ++c) acc[c] = 0.f;
  #pragma unroll
  for (int it = 0; it < 8; ++it) {
    const int unit = it * 64 + lane;           // hidden unit 0..511
    const float h = src[((unit >> 4) << 6) + ((unit & 15) << 2) + bp];
    #pragma unroll
    for (int c = 0; c < Cn; ++c) acc[c] += h * wfc[c * Hn + unit];
  }
  #pragma unroll
  for (int c = 0; c < Cn; ++c) {
    #pragma unroll
    for (int m = 1; m < 64; m <<= 1) acc[c] += __shfl_xor(acc[c], m);
  }
  if (lane == 0) {
    #pragma unroll
    for (int c = 0; c < Cn; ++c) out[(size_t)bt * Cn + c] = acc[c] + b_fc[c];
  }
}

// Fallback if workspace too small: one block per batch, no inter-block comms.
__global__ __launch_bounds__(512) void gru_fallback(
    const float* __restrict__ x, const float* __restrict__ w_ih,
    const float* __restrict__ w_hh, const float* __restrict__ b_ih,
    const float* __restrict__ b_hh, const float* __restrict__ w_fc,
    const float* __restrict__ b_fc, float* __restrict__ out)
{
  const int b = blockIdx.x;
  const int tid = threadIdx.x;
  __shared__ float hsh[Hn];
  __shared__ float xsh[Dn];
  hsh[tid] = 0.f;
  __syncthreads();
  for (int t = 0; t < Tn; ++t) {
    if (tid < Dn) xsh[tid] = x[((size_t)b * Tn + t) * Dn + tid];
    __syncthreads();
    const int u = tid;
    float gxr = 0.f, gxz = 0.f, gxn = 0.f;
    for (int d = 0; d < Dn; ++d) {
      const float xv = xsh[d];
      gxr += w_ih[(size_t)u * Dn + d] * xv;
      gxz += w_ih[(size_t)(Hn + u) * Dn + d] * xv;
      gxn += w_ih[(size_t)(2 * Hn + u) * Dn + d] * xv;
    }
    float ghr = 0.f, ghz = 0.f, ghn = 0.f;
    for (int k = 0; k < Hn; ++k) {
      const float hv = hsh[k];
      ghr += w_hh[(size_t)u * Hn + k] * hv;
      ghz += w_hh[(size_t)(Hn + u) * Hn + k] * hv;
      ghn += w_hh[(size_t)(2 * Hn + u) * Hn + k] * hv;
    }
    const float r = sigmoidf_(gxr + b_ih[u] + ghr + b_hh[u]);
    const float z = sigmoidf_(gxz + b_ih[Hn + u] + ghz + b_hh[Hn + u]);
    const float n = tanhf(gxn + b_ih[2 * Hn + u] + r * (ghn + b_hh[2 * Hn + u]));
    const float hold = hsh[u];
    __syncthreads();
    hsh[u] = (1.f - z) * n + z * hold;
    __syncthreads();
    if (tid < 320) {
      const int c = tid >> 5, l = tid & 31;
      float a = 0.f;
      for (int kk = 0; kk < 16; ++kk) {
        const int j = l * 16 + kk;
        a += hsh[j] * w_fc[c * Hn + j];
      }
      a += __shfl_xor(a, 1); a += __shfl_xor(a, 2); a += __shfl_xor(a, 4);
      a += __shfl_xor(a, 8); a += __shfl_xor(a, 16);
      if (l == 0) out[((size_t)b * Tn + t) * Cn + c] = a + b_fc[c];
    }
    __syncthreads();
  }
}

extern "C" void kernel_launch(void* const* d_in, const int* in_sizes, int n_in,
                              void* d_out, int out_size, void* d_ws, size_t ws_size,
                              hipStream_t stream) {
  const float* x    = (const float*)d_in[0];
  const float* w_ih = (const float*)d_in[1];
  const float* w_hh = (const float*)d_in[2];
  const float* b_ih = (const float*)d_in[3];
  const float* b_hh = (const float*)d_in[4];
  const float* w_fc = (const float*)d_in[5];
  const float* b_fc = (const float*)d_in[6];
  float* out = (float*)d_out;

  const size_t hs_bytes  = (size_t)Tn * NBG * XW * sizeof(float);              // 128 MiB
  const size_t xch_bytes = (size_t)2 * NBG * XW * sizeof(unsigned long long);  // 256 KiB

  if (ws_size >= hs_bytes) {
    float* hs = (float*)d_ws;
    // exchange ring lives in d_out (2.6 MB); gru_fc fully overwrites it after.
    unsigned long long* xchg = (unsigned long long*)d_out;
    hipMemsetAsync(xchg, 0, xch_bytes, stream);  // clear tags each launch (graph-safe)
    hipLaunchKernelGGL(gru_main, dim3(NG * NBG), dim3(NTH), 0, stream,
                       x, w_ih, w_hh, b_ih, b_hh, hs, xchg);
    hipLaunchKernelGGL(gru_fc, dim3((Bsz * Tn) / 4), dim3(256), 0, stream,
                       hs, w_fc, b_fc, out);
  } else {
    hipLaunchKernelGGL(gru_fallback, dim3(Bsz), dim3(512), 0, stream,
                       x, w_ih, w_hh, b_ih, b_hh, w_fc, b_fc, out);
  }
}